// Round 3
// baseline (10305.906 us; speedup 1.0000x reference)
//
#include <hip/hip_runtime.h>
#include <hip/hip_bf16.h>
#include <math.h>

// Problem constants (GQA attention block)
#define HID 2048
#define NH 16      // num query heads
#define NKV 4      // kv heads
#define HD 128     // head dim
#define GQ 4       // heads per kv group
#define BATCH 2

// ---------------------------------------------------------------------------
// Tiled fp32 GEMM with bias, 128x128 tile, BK=16, 256 threads, 8x8 microtile.
// 1 FMA per LDS byte read -> balanced against the 128 B/cyc LDS ceiling.
// As padded to stride 132: transposed staging stores go 4-way -> 2-way (free).
// ---------------------------------------------------------------------------
__global__ __launch_bounds__(256) void gemm_bias_128(
    const float* __restrict__ A, const float* __restrict__ W,
    const float* __restrict__ bias, float* __restrict__ C,
    int M, int N, int K) {
  __shared__ float As[16][132];  // transposed A tile: As[k][m], padded
  __shared__ float Ws[16][128];  // Ws[k][n]
  const int tid = threadIdx.x;
  const int row0 = blockIdx.y * 128;
  const int col0 = blockIdx.x * 128;
  const int ty = tid >> 4;   // 0..15 -> rows ty*8..ty*8+7
  const int tx = tid & 15;   // 0..15 -> cols tx*8..tx*8+7

  float acc[8][8] = {};

  for (int kt = 0; kt < K; kt += 16) {
    // Stage A tile (128 rows x 16 k), transposed: 2 float4 per thread
#pragma unroll
    for (int i = 0; i < 2; ++i) {
      int idx = tid + i * 256;   // 0..511
      int r = idx >> 2;          // 0..127
      int c4 = (idx & 3) * 4;    // 0,4,8,12
      float4 av = *reinterpret_cast<const float4*>(
          &A[(size_t)(row0 + r) * K + kt + c4]);
      As[c4 + 0][r] = av.x;
      As[c4 + 1][r] = av.y;
      As[c4 + 2][r] = av.z;
      As[c4 + 3][r] = av.w;
    }
    // Stage W tile (16 k x 128 n): 2 float4 per thread
#pragma unroll
    for (int i = 0; i < 2; ++i) {
      int idx = tid + i * 256;
      int r = idx >> 5;          // 0..15
      int c4 = (idx & 31) * 4;   // 0..124
      *reinterpret_cast<float4*>(&Ws[r][c4]) =
          *reinterpret_cast<const float4*>(
              &W[(size_t)(kt + r) * N + col0 + c4]);
    }
    __syncthreads();
#pragma unroll
    for (int kk = 0; kk < 16; ++kk) {
      float4 a0 = *reinterpret_cast<const float4*>(&As[kk][ty * 8]);
      float4 a1 = *reinterpret_cast<const float4*>(&As[kk][ty * 8 + 4]);
      float4 b0 = *reinterpret_cast<const float4*>(&Ws[kk][tx * 8]);
      float4 b1 = *reinterpret_cast<const float4*>(&Ws[kk][tx * 8 + 4]);
      float av[8] = {a0.x, a0.y, a0.z, a0.w, a1.x, a1.y, a1.z, a1.w};
      float bv[8] = {b0.x, b0.y, b0.z, b0.w, b1.x, b1.y, b1.z, b1.w};
#pragma unroll
      for (int i = 0; i < 8; ++i)
#pragma unroll
        for (int j = 0; j < 8; ++j) acc[i][j] += av[i] * bv[j];
    }
    __syncthreads();
  }

#pragma unroll
  for (int i = 0; i < 8; ++i) {
    int r = row0 + ty * 8 + i;
#pragma unroll
    for (int j4 = 0; j4 < 2; ++j4) {
      int c = col0 + tx * 8 + j4 * 4;
      float4 o;
      o.x = acc[i][j4 * 4 + 0] + bias[c + 0];
      o.y = acc[i][j4 * 4 + 1] + bias[c + 1];
      o.z = acc[i][j4 * 4 + 2] + bias[c + 2];
      o.w = acc[i][j4 * 4 + 3] + bias[c + 3];
      *reinterpret_cast<float4*>(&C[(size_t)r * N + c]) = o;
    }
  }
}

// ---------------------------------------------------------------------------
// Fused K+V projection: same 128x128 tile GEMM, but the grid's x dimension
// spans [wk | wv] (each N=512). Blocks with blockIdx.x < 4 compute k, the
// rest compute v. Gives 8x32 = 256 blocks (one per CU) instead of two
// half-occupancy 64-tile dispatches.
// ---------------------------------------------------------------------------
__global__ __launch_bounds__(256) void gemm_bias_kv(
    const float* __restrict__ A,
    const float* __restrict__ Wk, const float* __restrict__ bk,
    float* __restrict__ Ck,
    const float* __restrict__ Wv, const float* __restrict__ bv,
    float* __restrict__ Cv,
    int M, int Nhalf, int K) {
  __shared__ float As[16][132];
  __shared__ float Ws[16][128];
  const int tid = threadIdx.x;
  const int row0 = blockIdx.y * 128;
  const int half = (int)blockIdx.x / (Nhalf / 128);   // 0 -> k, 1 -> v
  const int col0 = ((int)blockIdx.x % (Nhalf / 128)) * 128;
  const float* W = half ? Wv : Wk;
  const float* bias = half ? bv : bk;
  float* C = half ? Cv : Ck;
  const int N = Nhalf;
  const int ty = tid >> 4;
  const int tx = tid & 15;

  float acc[8][8] = {};

  for (int kt = 0; kt < K; kt += 16) {
#pragma unroll
    for (int i = 0; i < 2; ++i) {
      int idx = tid + i * 256;
      int r = idx >> 2;
      int c4 = (idx & 3) * 4;
      float4 av = *reinterpret_cast<const float4*>(
          &A[(size_t)(row0 + r) * K + kt + c4]);
      As[c4 + 0][r] = av.x;
      As[c4 + 1][r] = av.y;
      As[c4 + 2][r] = av.z;
      As[c4 + 3][r] = av.w;
    }
#pragma unroll
    for (int i = 0; i < 2; ++i) {
      int idx = tid + i * 256;
      int r = idx >> 5;
      int c4 = (idx & 31) * 4;
      *reinterpret_cast<float4*>(&Ws[r][c4]) =
          *reinterpret_cast<const float4*>(
              &W[(size_t)(kt + r) * N + col0 + c4]);
    }
    __syncthreads();
#pragma unroll
    for (int kk = 0; kk < 16; ++kk) {
      float4 a0 = *reinterpret_cast<const float4*>(&As[kk][ty * 8]);
      float4 a1 = *reinterpret_cast<const float4*>(&As[kk][ty * 8 + 4]);
      float4 b0 = *reinterpret_cast<const float4*>(&Ws[kk][tx * 8]);
      float4 b1 = *reinterpret_cast<const float4*>(&Ws[kk][tx * 8 + 4]);
      float av[8] = {a0.x, a0.y, a0.z, a0.w, a1.x, a1.y, a1.z, a1.w};
      float bv8[8] = {b0.x, b0.y, b0.z, b0.w, b1.x, b1.y, b1.z, b1.w};
#pragma unroll
      for (int i = 0; i < 8; ++i)
#pragma unroll
        for (int j = 0; j < 8; ++j) acc[i][j] += av[i] * bv8[j];
    }
    __syncthreads();
  }

#pragma unroll
  for (int i = 0; i < 8; ++i) {
    int r = row0 + ty * 8 + i;
#pragma unroll
    for (int j4 = 0; j4 < 2; ++j4) {
      int c = col0 + tx * 8 + j4 * 4;
      float4 o;
      o.x = acc[i][j4 * 4 + 0] + bias[c + 0];
      o.y = acc[i][j4 * 4 + 1] + bias[c + 1];
      o.z = acc[i][j4 * 4 + 2] + bias[c + 2];
      o.w = acc[i][j4 * 4 + 3] + bias[c + 3];
      *reinterpret_cast<float4*>(&C[(size_t)r * N + c]) = o;
    }
  }
}

// ---------------------------------------------------------------------------
// Flash-style causal GQA attention.
// Grid: (S/64, NH, BATCH). Block: 256 threads.
// Q tile [64][128] in LDS, loop K/V tiles of 64 with online softmax.
// LDS rows are XOR-swizzled at float4 granularity: chunk c of row r is
// stored at chunk (c ^ ((r>>2)&7)) to avoid bank conflicts on the
// 16-distinct-row reads in the score loop.
// ---------------------------------------------------------------------------
__global__ __launch_bounds__(256) void gqa_attn(
    const float* __restrict__ Q, const float* __restrict__ Kg,
    const float* __restrict__ Vg, float* __restrict__ O, int S) {
  __shared__ float Qs[64][128];
  __shared__ float Ks[64][128];
  __shared__ float Vs[64][128];
  __shared__ float Ps[64][68];   // +4 pad -> 2-way-max conflicts on P reads
  __shared__ float red[64][16];
  __shared__ float m_s[64], l_s[64], alpha_s[64];

  const int tid = threadIdx.x;
  const int q0 = blockIdx.x * 64;
  const int hq = blockIdx.y;
  const int b = blockIdx.z;
  const int kvh = hq >> 2;  // GQ = 4
  const float scale = 0.08838834764831845f;  // 1/sqrt(128)

  const float* Qb = Q + ((size_t)b * S) * (NH * HD) + hq * HD;
  const float* Kb = Kg + ((size_t)b * S) * (NKV * HD) + kvh * HD;
  const float* Vb = Vg + ((size_t)b * S) * (NKV * HD) + kvh * HD;

  const int rg = tid >> 4;  // 0..15: rows rg*4 .. rg*4+3
  const int cg = tid & 15;  // 0..15: cols cg*4 .. cg*4+3 (and d-groups for O)

  // Stage Q tile (swizzled)
#pragma unroll
  for (int i = 0; i < 8; ++i) {
    int idx = tid + i * 256;  // 0..2047 float4 chunks
    int r = idx >> 5;         // row 0..63
    int c = idx & 31;         // chunk 0..31
    int sc = c ^ ((r >> 2) & 7);
    *reinterpret_cast<float4*>(&Qs[r][sc * 4]) =
        *reinterpret_cast<const float4*>(
            &Qb[(size_t)(q0 + r) * (NH * HD) + c * 4]);
  }
  if (tid < 64) {
    m_s[tid] = -INFINITY;
    l_s[tid] = 0.f;
  }
  float Oacc[4][8] = {};  // rows rg*4+i; d = cg*4+dd and 64+cg*4+dd
  __syncthreads();

  const int ntiles = q0 / 64 + 1;  // causal: only tiles with keys <= q0+63
  for (int kt = 0; kt < ntiles; ++kt) {
    const int k0 = kt * 64;
    // Stage K and V tiles (swizzled)
#pragma unroll
    for (int i = 0; i < 8; ++i) {
      int idx = tid + i * 256;
      int r = idx >> 5;
      int c = idx & 31;
      int sc = c ^ ((r >> 2) & 7);
      *reinterpret_cast<float4*>(&Ks[r][sc * 4]) =
          *reinterpret_cast<const float4*>(
              &Kb[(size_t)(k0 + r) * (NKV * HD) + c * 4]);
      *reinterpret_cast<float4*>(&Vs[r][sc * 4]) =
          *reinterpret_cast<const float4*>(
              &Vb[(size_t)(k0 + r) * (NKV * HD) + c * 4]);
    }
    __syncthreads();

    // ---- scores: 4x4 per thread over d=128 ----
    float s[4][4] = {};
#pragma unroll
    for (int c = 0; c < 32; ++c) {
      const int qsc = (c ^ (rg & 7)) * 4;  // (row>>2)&7 == rg&7
      const int ksc = (c ^ (cg & 7)) * 4;  // (col>>2)&7 == cg&7
      float4 qv[4], kv[4];
#pragma unroll
      for (int i = 0; i < 4; ++i)
        qv[i] = *reinterpret_cast<const float4*>(&Qs[rg * 4 + i][qsc]);
#pragma unroll
      for (int j = 0; j < 4; ++j)
        kv[j] = *reinterpret_cast<const float4*>(&Ks[cg * 4 + j][ksc]);
#pragma unroll
      for (int i = 0; i < 4; ++i)
#pragma unroll
        for (int j = 0; j < 4; ++j)
          s[i][j] += qv[i].x * kv[j].x + qv[i].y * kv[j].y +
                     qv[i].z * kv[j].z + qv[i].w * kv[j].w;
    }

    // ---- scale + causal mask + partial row max ----
#pragma unroll
    for (int i = 0; i < 4; ++i) {
      const int qi = q0 + rg * 4 + i;
      float mx = -INFINITY;
#pragma unroll
      for (int j = 0; j < 4; ++j) {
        const int kj = k0 + cg * 4 + j;
        s[i][j] = (kj <= qi) ? s[i][j] * scale : -INFINITY;
        mx = fmaxf(mx, s[i][j]);
      }
      red[rg * 4 + i][cg] = mx;
    }
    __syncthreads();
    if (tid < 64) {
      float mx = red[tid][0];
#pragma unroll
      for (int c2 = 1; c2 < 16; ++c2) mx = fmaxf(mx, red[tid][c2]);
      const float m_new = fmaxf(m_s[tid], mx);
      alpha_s[tid] = __expf(m_s[tid] - m_new);
      m_s[tid] = m_new;
    }
    __syncthreads();

    // ---- P = exp(s - m), partial row sums, rescale O ----
#pragma unroll
    for (int i = 0; i < 4; ++i) {
      const int r = rg * 4 + i;
      const float m = m_s[r];
      float sum = 0.f;
#pragma unroll
      for (int j = 0; j < 4; ++j) {
        const float p = __expf(s[i][j] - m);
        Ps[r][cg * 4 + j] = p;
        sum += p;
      }
      red[r][cg] = sum;
      const float a = alpha_s[r];
#pragma unroll
      for (int dd = 0; dd < 8; ++dd) Oacc[i][dd] *= a;
    }
    __syncthreads();
    if (tid < 64) {
      float sum = 0.f;
#pragma unroll
      for (int c2 = 0; c2 < 16; ++c2) sum += red[tid][c2];
      l_s[tid] = l_s[tid] * alpha_s[tid] + sum;
    }

    // ---- O += P @ V ----
#pragma unroll
    for (int jc = 0; jc < 16; ++jc) {
      const int jj0 = jc * 4;
      float4 pv[4];
#pragma unroll
      for (int i = 0; i < 4; ++i)
        pv[i] = *reinterpret_cast<const float4*>(&Ps[rg * 4 + i][jj0]);
#pragma unroll
      for (int j = 0; j < 4; ++j) {
        const int vr = jj0 + j;
        const int sw = (vr >> 2) & 7;
        float4 v1 = *reinterpret_cast<const float4*>(&Vs[vr][(cg ^ sw) * 4]);
        float4 v2 =
            *reinterpret_cast<const float4*>(&Vs[vr][((cg + 16) ^ sw) * 4]);
#pragma unroll
        for (int i = 0; i < 4; ++i) {
          const float p = reinterpret_cast<const float*>(&pv[i])[j];
          Oacc[i][0] += p * v1.x;
          Oacc[i][1] += p * v1.y;
          Oacc[i][2] += p * v1.z;
          Oacc[i][3] += p * v1.w;
          Oacc[i][4] += p * v2.x;
          Oacc[i][5] += p * v2.y;
          Oacc[i][6] += p * v2.z;
          Oacc[i][7] += p * v2.w;
        }
      }
    }
    __syncthreads();  // protect Ks/Vs/Ps/red for next tile; l_s for epilogue
  }

  // ---- epilogue: O / l ----
  float* Ob = O + ((size_t)b * S) * (NH * HD) + hq * HD;
#pragma unroll
  for (int i = 0; i < 4; ++i) {
    const int r = rg * 4 + i;
    const float inv = 1.0f / l_s[r];
    float4 o1, o2;
    o1.x = Oacc[i][0] * inv;
    o1.y = Oacc[i][1] * inv;
    o1.z = Oacc[i][2] * inv;
    o1.w = Oacc[i][3] * inv;
    o2.x = Oacc[i][4] * inv;
    o2.y = Oacc[i][5] * inv;
    o2.z = Oacc[i][6] * inv;
    o2.w = Oacc[i][7] * inv;
    *reinterpret_cast<float4*>(
        &Ob[(size_t)(q0 + r) * (NH * HD) + cg * 4]) = o1;
    *reinterpret_cast<float4*>(
        &Ob[(size_t)(q0 + r) * (NH * HD) + 64 + cg * 4]) = o2;
  }
}

// ---------------------------------------------------------------------------
extern "C" void kernel_launch(void* const* d_in, const int* in_sizes, int n_in,
                              void* d_out, int out_size, void* d_ws,
                              size_t ws_size, hipStream_t stream) {
  const float* x = (const float*)d_in[0];
  const float* wq = (const float*)d_in[1];
  const float* bq = (const float*)d_in[2];
  const float* wk = (const float*)d_in[3];
  const float* bk = (const float*)d_in[4];
  const float* wv = (const float*)d_in[5];
  const float* bv = (const float*)d_in[6];
  const float* wo = (const float*)d_in[7];
  const float* bo = (const float*)d_in[8];
  float* out = (float*)d_out;

  const int M = in_sizes[0] / HID;  // B*S = 4096
  const int S = M / BATCH;          // 2048

  float* q = (float*)d_ws;                       // M * 2048
  float* k = q + (size_t)M * (NH * HD);          // M * 512
  float* v = k + (size_t)M * (NKV * HD);         // M * 512
  float* attn = v + (size_t)M * (NKV * HD);      // M * 2048

  dim3 blk(256);
  // Q projection: 16x32 = 512 blocks
  gemm_bias_128<<<dim3((NH * HD) / 128, M / 128), blk, 0, stream>>>(
      x, wq, bq, q, M, NH * HD, HID);
  // Fused K+V projection: 8x32 = 256 blocks (one per CU)
  gemm_bias_kv<<<dim3((2 * NKV * HD) / 128, M / 128), blk, 0, stream>>>(
      x, wk, bk, k, wv, bv, v, M, NKV * HD, HID);
  // Attention
  gqa_attn<<<dim3(S / 64, NH, BATCH), blk, 0, stream>>>(q, k, v, attn, S);
  // Output projection: 512 blocks
  gemm_bias_128<<<dim3(HID / 128, M / 128), blk, 0, stream>>>(
      attn, wo, bo, out, M, HID, HID);
}

// Round 4
// 2601.586 us; speedup vs baseline: 3.9614x; 3.9614x over previous
//
#include <hip/hip_runtime.h>
#include <hip/hip_bf16.h>
#include <math.h>

// Problem constants (GQA attention block)
#define HID 2048
#define NH 16      // num query heads
#define NKV 4      // kv heads
#define HD 128     // head dim
#define GQ 4       // heads per kv group
#define BATCH 2

// ---------------------------------------------------------------------------
// Tiled fp32 GEMM with bias, 128x128 tile, BK=16, 256 threads, 8x8 microtile.
// 1 FMA per LDS byte read -> balanced against the 128 B/cyc LDS ceiling.
// As padded to stride 132: transposed staging stores go 4-way -> 2-way (free).
// ---------------------------------------------------------------------------
__global__ __launch_bounds__(256) void gemm_bias_128(
    const float* __restrict__ A, const float* __restrict__ W,
    const float* __restrict__ bias, float* __restrict__ C,
    int M, int N, int K) {
  __shared__ float As[16][132];  // transposed A tile: As[k][m], padded
  __shared__ float Ws[16][128];  // Ws[k][n]
  const int tid = threadIdx.x;
  const int row0 = blockIdx.y * 128;
  const int col0 = blockIdx.x * 128;
  const int ty = tid >> 4;   // 0..15 -> rows ty*8..ty*8+7
  const int tx = tid & 15;   // 0..15 -> cols tx*8..tx*8+7

  float acc[8][8] = {};

  for (int kt = 0; kt < K; kt += 16) {
    // Stage A tile (128 rows x 16 k), transposed: 2 float4 per thread
#pragma unroll
    for (int i = 0; i < 2; ++i) {
      int idx = tid + i * 256;   // 0..511
      int r = idx >> 2;          // 0..127
      int c4 = (idx & 3) * 4;    // 0,4,8,12
      float4 av = *reinterpret_cast<const float4*>(
          &A[(size_t)(row0 + r) * K + kt + c4]);
      As[c4 + 0][r] = av.x;
      As[c4 + 1][r] = av.y;
      As[c4 + 2][r] = av.z;
      As[c4 + 3][r] = av.w;
    }
    // Stage W tile (16 k x 128 n): 2 float4 per thread
#pragma unroll
    for (int i = 0; i < 2; ++i) {
      int idx = tid + i * 256;
      int r = idx >> 5;          // 0..15
      int c4 = (idx & 31) * 4;   // 0..124
      *reinterpret_cast<float4*>(&Ws[r][c4]) =
          *reinterpret_cast<const float4*>(
              &W[(size_t)(kt + r) * N + col0 + c4]);
    }
    __syncthreads();
#pragma unroll
    for (int kk = 0; kk < 16; ++kk) {
      float4 a0 = *reinterpret_cast<const float4*>(&As[kk][ty * 8]);
      float4 a1 = *reinterpret_cast<const float4*>(&As[kk][ty * 8 + 4]);
      float4 b0 = *reinterpret_cast<const float4*>(&Ws[kk][tx * 8]);
      float4 b1 = *reinterpret_cast<const float4*>(&Ws[kk][tx * 8 + 4]);
      float av[8] = {a0.x, a0.y, a0.z, a0.w, a1.x, a1.y, a1.z, a1.w};
      float bv[8] = {b0.x, b0.y, b0.z, b0.w, b1.x, b1.y, b1.z, b1.w};
#pragma unroll
      for (int i = 0; i < 8; ++i)
#pragma unroll
        for (int j = 0; j < 8; ++j) acc[i][j] += av[i] * bv[j];
    }
    __syncthreads();
  }

#pragma unroll
  for (int i = 0; i < 8; ++i) {
    int r = row0 + ty * 8 + i;
#pragma unroll
    for (int j4 = 0; j4 < 2; ++j4) {
      int c = col0 + tx * 8 + j4 * 4;
      float4 o;
      o.x = acc[i][j4 * 4 + 0] + bias[c + 0];
      o.y = acc[i][j4 * 4 + 1] + bias[c + 1];
      o.z = acc[i][j4 * 4 + 2] + bias[c + 2];
      o.w = acc[i][j4 * 4 + 3] + bias[c + 3];
      *reinterpret_cast<float4*>(&C[(size_t)r * N + c]) = o;
    }
  }
}

// ---------------------------------------------------------------------------
// Fused K+V projection: same 128x128 tile GEMM, grid x spans [wk | wv].
// 8x32 = 256 blocks (one per CU).
// ---------------------------------------------------------------------------
__global__ __launch_bounds__(256) void gemm_bias_kv(
    const float* __restrict__ A,
    const float* __restrict__ Wk, const float* __restrict__ bk,
    float* __restrict__ Ck,
    const float* __restrict__ Wv, const float* __restrict__ bv,
    float* __restrict__ Cv,
    int M, int Nhalf, int K) {
  __shared__ float As[16][132];
  __shared__ float Ws[16][128];
  const int tid = threadIdx.x;
  const int row0 = blockIdx.y * 128;
  const int half = (int)blockIdx.x / (Nhalf / 128);   // 0 -> k, 1 -> v
  const int col0 = ((int)blockIdx.x % (Nhalf / 128)) * 128;
  const float* W = half ? Wv : Wk;
  const float* bias = half ? bv : bk;
  float* C = half ? Cv : Ck;
  const int N = Nhalf;
  const int ty = tid >> 4;
  const int tx = tid & 15;

  float acc[8][8] = {};

  for (int kt = 0; kt < K; kt += 16) {
#pragma unroll
    for (int i = 0; i < 2; ++i) {
      int idx = tid + i * 256;
      int r = idx >> 2;
      int c4 = (idx & 3) * 4;
      float4 av = *reinterpret_cast<const float4*>(
          &A[(size_t)(row0 + r) * K + kt + c4]);
      As[c4 + 0][r] = av.x;
      As[c4 + 1][r] = av.y;
      As[c4 + 2][r] = av.z;
      As[c4 + 3][r] = av.w;
    }
#pragma unroll
    for (int i = 0; i < 2; ++i) {
      int idx = tid + i * 256;
      int r = idx >> 5;
      int c4 = (idx & 31) * 4;
      *reinterpret_cast<float4*>(&Ws[r][c4]) =
          *reinterpret_cast<const float4*>(
              &W[(size_t)(kt + r) * N + col0 + c4]);
    }
    __syncthreads();
#pragma unroll
    for (int kk = 0; kk < 16; ++kk) {
      float4 a0 = *reinterpret_cast<const float4*>(&As[kk][ty * 8]);
      float4 a1 = *reinterpret_cast<const float4*>(&As[kk][ty * 8 + 4]);
      float4 b0 = *reinterpret_cast<const float4*>(&Ws[kk][tx * 8]);
      float4 b1 = *reinterpret_cast<const float4*>(&Ws[kk][tx * 8 + 4]);
      float av[8] = {a0.x, a0.y, a0.z, a0.w, a1.x, a1.y, a1.z, a1.w};
      float bv8[8] = {b0.x, b0.y, b0.z, b0.w, b1.x, b1.y, b1.z, b1.w};
#pragma unroll
      for (int i = 0; i < 8; ++i)
#pragma unroll
        for (int j = 0; j < 8; ++j) acc[i][j] += av[i] * bv8[j];
    }
    __syncthreads();
  }

#pragma unroll
  for (int i = 0; i < 8; ++i) {
    int r = row0 + ty * 8 + i;
#pragma unroll
    for (int j4 = 0; j4 < 2; ++j4) {
      int c = col0 + tx * 8 + j4 * 4;
      float4 o;
      o.x = acc[i][j4 * 4 + 0] + bias[c + 0];
      o.y = acc[i][j4 * 4 + 1] + bias[c + 1];
      o.z = acc[i][j4 * 4 + 2] + bias[c + 2];
      o.w = acc[i][j4 * 4 + 3] + bias[c + 3];
      *reinterpret_cast<float4*>(&C[(size_t)r * N + c]) = o;
    }
  }
}

// ---------------------------------------------------------------------------
// Flash-style causal GQA attention.
// Grid: (S/64, NH, BATCH). Block: 256 threads.
// R3 spill fix: the fully-unrolled score/PV loops let the scheduler hoist
// ~256+ live LDS loads -> VGPR cap 256 + 45 KB/thread scratch spill ->
// 20 GB HBM traffic -> 9 ms. Partial unroll (4 / 2) caps live ranges;
// __launch_bounds__(256,1) lifts the VGPR cap to 512 (free: 118 KB LDS
// already limits us to 1 block/CU = 1 wave/SIMD).
// ---------------------------------------------------------------------------
__global__ __launch_bounds__(256, 1) void gqa_attn(
    const float* __restrict__ Q, const float* __restrict__ Kg,
    const float* __restrict__ Vg, float* __restrict__ O, int S) {
  __shared__ float Qs[64][128];
  __shared__ float Ks[64][128];
  __shared__ float Vs[64][128];
  __shared__ float Ps[64][68];   // +4 pad -> 2-way-max conflicts on P reads
  __shared__ float red[64][16];
  __shared__ float m_s[64], l_s[64], alpha_s[64];

  const int tid = threadIdx.x;
  const int q0 = blockIdx.x * 64;
  const int hq = blockIdx.y;
  const int b = blockIdx.z;
  const int kvh = hq >> 2;  // GQ = 4
  const float scale = 0.08838834764831845f;  // 1/sqrt(128)

  const float* Qb = Q + ((size_t)b * S) * (NH * HD) + hq * HD;
  const float* Kb = Kg + ((size_t)b * S) * (NKV * HD) + kvh * HD;
  const float* Vb = Vg + ((size_t)b * S) * (NKV * HD) + kvh * HD;

  const int rg = tid >> 4;  // 0..15: rows rg*4 .. rg*4+3
  const int cg = tid & 15;  // 0..15: cols cg*4 .. cg*4+3 (and d-groups for O)

  // Stage Q tile (swizzled)
#pragma unroll
  for (int i = 0; i < 8; ++i) {
    int idx = tid + i * 256;  // 0..2047 float4 chunks
    int r = idx >> 5;         // row 0..63
    int c = idx & 31;         // chunk 0..31
    int sc = c ^ ((r >> 2) & 7);
    *reinterpret_cast<float4*>(&Qs[r][sc * 4]) =
        *reinterpret_cast<const float4*>(
            &Qb[(size_t)(q0 + r) * (NH * HD) + c * 4]);
  }
  if (tid < 64) {
    m_s[tid] = -INFINITY;
    l_s[tid] = 0.f;
  }
  float Oacc[4][8] = {};  // rows rg*4+i; d = cg*4+dd and 64+cg*4+dd
  __syncthreads();

  const int ntiles = q0 / 64 + 1;  // causal: only tiles with keys <= q0+63
  for (int kt = 0; kt < ntiles; ++kt) {
    const int k0 = kt * 64;
    // Stage K and V tiles (swizzled)
#pragma unroll
    for (int i = 0; i < 8; ++i) {
      int idx = tid + i * 256;
      int r = idx >> 5;
      int c = idx & 31;
      int sc = c ^ ((r >> 2) & 7);
      *reinterpret_cast<float4*>(&Ks[r][sc * 4]) =
          *reinterpret_cast<const float4*>(
              &Kb[(size_t)(k0 + r) * (NKV * HD) + c * 4]);
      *reinterpret_cast<float4*>(&Vs[r][sc * 4]) =
          *reinterpret_cast<const float4*>(
              &Vb[(size_t)(k0 + r) * (NKV * HD) + c * 4]);
    }
    __syncthreads();

    // ---- scores: 4x4 per thread over d=128 (unroll 4: no spill) ----
    float s[4][4] = {};
#pragma unroll 4
    for (int c = 0; c < 32; ++c) {
      const int qsc = (c ^ (rg & 7)) * 4;  // (row>>2)&7 == rg&7
      const int ksc = (c ^ (cg & 7)) * 4;  // (col>>2)&7 == cg&7
      float4 qv[4], kv[4];
#pragma unroll
      for (int i = 0; i < 4; ++i)
        qv[i] = *reinterpret_cast<const float4*>(&Qs[rg * 4 + i][qsc]);
#pragma unroll
      for (int j = 0; j < 4; ++j)
        kv[j] = *reinterpret_cast<const float4*>(&Ks[cg * 4 + j][ksc]);
#pragma unroll
      for (int i = 0; i < 4; ++i)
#pragma unroll
        for (int j = 0; j < 4; ++j)
          s[i][j] += qv[i].x * kv[j].x + qv[i].y * kv[j].y +
                     qv[i].z * kv[j].z + qv[i].w * kv[j].w;
    }

    // ---- scale + causal mask + partial row max ----
#pragma unroll
    for (int i = 0; i < 4; ++i) {
      const int qi = q0 + rg * 4 + i;
      float mx = -INFINITY;
#pragma unroll
      for (int j = 0; j < 4; ++j) {
        const int kj = k0 + cg * 4 + j;
        s[i][j] = (kj <= qi) ? s[i][j] * scale : -INFINITY;
        mx = fmaxf(mx, s[i][j]);
      }
      red[rg * 4 + i][cg] = mx;
    }
    __syncthreads();
    if (tid < 64) {
      float mx = red[tid][0];
#pragma unroll
      for (int c2 = 1; c2 < 16; ++c2) mx = fmaxf(mx, red[tid][c2]);
      const float m_new = fmaxf(m_s[tid], mx);
      alpha_s[tid] = __expf(m_s[tid] - m_new);
      m_s[tid] = m_new;
    }
    __syncthreads();

    // ---- P = exp(s - m), partial row sums, rescale O ----
#pragma unroll
    for (int i = 0; i < 4; ++i) {
      const int r = rg * 4 + i;
      const float m = m_s[r];
      float sum = 0.f;
#pragma unroll
      for (int j = 0; j < 4; ++j) {
        const float p = __expf(s[i][j] - m);
        Ps[r][cg * 4 + j] = p;
        sum += p;
      }
      red[r][cg] = sum;
      const float a = alpha_s[r];
#pragma unroll
      for (int dd = 0; dd < 8; ++dd) Oacc[i][dd] *= a;
    }
    __syncthreads();
    if (tid < 64) {
      float sum = 0.f;
#pragma unroll
      for (int c2 = 0; c2 < 16; ++c2) sum += red[tid][c2];
      l_s[tid] = l_s[tid] * alpha_s[tid] + sum;
    }

    // ---- O += P @ V (unroll 2: no spill) ----
#pragma unroll 2
    for (int jc = 0; jc < 16; ++jc) {
      const int jj0 = jc * 4;
      float4 pv[4];
#pragma unroll
      for (int i = 0; i < 4; ++i)
        pv[i] = *reinterpret_cast<const float4*>(&Ps[rg * 4 + i][jj0]);
#pragma unroll
      for (int j = 0; j < 4; ++j) {
        const int vr = jj0 + j;
        const int sw = (vr >> 2) & 7;
        float4 v1 = *reinterpret_cast<const float4*>(&Vs[vr][(cg ^ sw) * 4]);
        float4 v2 =
            *reinterpret_cast<const float4*>(&Vs[vr][((cg + 16) ^ sw) * 4]);
#pragma unroll
        for (int i = 0; i < 4; ++i) {
          const float p = reinterpret_cast<const float*>(&pv[i])[j];
          Oacc[i][0] += p * v1.x;
          Oacc[i][1] += p * v1.y;
          Oacc[i][2] += p * v1.z;
          Oacc[i][3] += p * v1.w;
          Oacc[i][4] += p * v2.x;
          Oacc[i][5] += p * v2.y;
          Oacc[i][6] += p * v2.z;
          Oacc[i][7] += p * v2.w;
        }
      }
    }
    __syncthreads();  // protect Ks/Vs/Ps/red for next tile; l_s for epilogue
  }

  // ---- epilogue: O / l ----
  float* Ob = O + ((size_t)b * S) * (NH * HD) + hq * HD;
#pragma unroll
  for (int i = 0; i < 4; ++i) {
    const int r = rg * 4 + i;
    const float inv = 1.0f / l_s[r];
    float4 o1, o2;
    o1.x = Oacc[i][0] * inv;
    o1.y = Oacc[i][1] * inv;
    o1.z = Oacc[i][2] * inv;
    o1.w = Oacc[i][3] * inv;
    o2.x = Oacc[i][4] * inv;
    o2.y = Oacc[i][5] * inv;
    o2.z = Oacc[i][6] * inv;
    o2.w = Oacc[i][7] * inv;
    *reinterpret_cast<float4*>(
        &Ob[(size_t)(q0 + r) * (NH * HD) + cg * 4]) = o1;
    *reinterpret_cast<float4*>(
        &Ob[(size_t)(q0 + r) * (NH * HD) + 64 + cg * 4]) = o2;
  }
}

// ---------------------------------------------------------------------------
extern "C" void kernel_launch(void* const* d_in, const int* in_sizes, int n_in,
                              void* d_out, int out_size, void* d_ws,
                              size_t ws_size, hipStream_t stream) {
  const float* x = (const float*)d_in[0];
  const float* wq = (const float*)d_in[1];
  const float* bq = (const float*)d_in[2];
  const float* wk = (const float*)d_in[3];
  const float* bk = (const float*)d_in[4];
  const float* wv = (const float*)d_in[5];
  const float* bv = (const float*)d_in[6];
  const float* wo = (const float*)d_in[7];
  const float* bo = (const float*)d_in[8];
  float* out = (float*)d_out;

  const int M = in_sizes[0] / HID;  // B*S = 4096
  const int S = M / BATCH;          // 2048

  float* q = (float*)d_ws;                       // M * 2048
  float* k = q + (size_t)M * (NH * HD);          // M * 512
  float* v = k + (size_t)M * (NKV * HD);         // M * 512
  float* attn = v + (size_t)M * (NKV * HD);      // M * 2048

  dim3 blk(256);
  // Q projection: 16x32 = 512 blocks
  gemm_bias_128<<<dim3((NH * HD) / 128, M / 128), blk, 0, stream>>>(
      x, wq, bq, q, M, NH * HD, HID);
  // Fused K+V projection: 8x32 = 256 blocks (one per CU)
  gemm_bias_kv<<<dim3((2 * NKV * HD) / 128, M / 128), blk, 0, stream>>>(
      x, wk, bk, k, wv, bv, v, M, NKV * HD, HID);
  // Attention
  gqa_attn<<<dim3(S / 64, NH, BATCH), blk, 0, stream>>>(q, k, v, attn, S);
  // Output projection: 512 blocks
  gemm_bias_128<<<dim3(HID / 128, M / 128), blk, 0, stream>>>(
      attn, wo, bo, out, M, HID, HID);
}

// Round 5
// 1768.057 us; speedup vs baseline: 5.8289x; 1.4714x over previous
//
#include <hip/hip_runtime.h>
#include <hip/hip_bf16.h>
#include <math.h>

// Problem constants (GQA attention block)
#define HID 2048
#define NH 16      // num query heads
#define NKV 4      // kv heads
#define HD 128     // head dim
#define GQ 4       // heads per kv group
#define BATCH 2

typedef short short8v __attribute__((ext_vector_type(8)));
typedef float f32x4 __attribute__((ext_vector_type(4)));

// fp32 -> bf16 with round-to-nearest-even (bit manipulation; finite values)
__device__ __forceinline__ ushort f2bf(float f) {
  uint u = __float_as_uint(f);
  uint r = (u + 0x7fffu + ((u >> 16) & 1u)) >> 16;
  return (ushort)r;
}

// LDS chunk swizzle: logical 8-bf16 chunk c of row r stored at c ^ s(r).
// Gives <=2-way bank aliasing on both staging writes and ds_read_b128
// fragment reads (row stride 32 bf16 = 64 B = 16 banks).
__device__ __forceinline__ int swz(int r) {
  return (r & 3) ^ ((r >> 2) & 3);
}

// ---------------------------------------------------------------------------
// Transpose-cast: W fp32 [K][N] -> Wt bf16 [N][K]. 32x32 tiles via LDS.
// Grid: (K/32, N/32), 256 threads.
// ---------------------------------------------------------------------------
__global__ __launch_bounds__(256) void tcast_kernel(
    const float* __restrict__ W, ushort* __restrict__ Wt, int K, int N) {
  __shared__ float T[32][33];
  const int k0 = blockIdx.x * 32;
  const int n0 = blockIdx.y * 32;
  const int t = threadIdx.x;
  const int r = t >> 3;          // 0..31
  const int c4 = (t & 7) * 4;    // 0..28
  float4 vin = *reinterpret_cast<const float4*>(
      &W[(size_t)(k0 + r) * N + n0 + c4]);
  T[c4 + 0][r] = vin.x;
  T[c4 + 1][r] = vin.y;
  T[c4 + 2][r] = vin.z;
  T[c4 + 3][r] = vin.w;
  __syncthreads();
  ushort4 o;
  o.x = f2bf(T[r][c4 + 0]);
  o.y = f2bf(T[r][c4 + 1]);
  o.z = f2bf(T[r][c4 + 2]);
  o.w = f2bf(T[r][c4 + 3]);
  *reinterpret_cast<ushort4*>(&Wt[(size_t)(n0 + r) * K + k0 + c4]) = o;
}

// ---------------------------------------------------------------------------
// bf16 MFMA GEMM: C[M,N] fp32 = A[M,K] * Bt[N,K]^T + bias.
// A is fp32 (converted during staging) if AF32, else bf16 (ushort).
// 128x128 tile, BK=32, 256 threads = 4 waves, each wave 64x64 via 4x4
// grid of 16x16x32 bf16 MFMAs. LDS swizzled (see swz).
// ---------------------------------------------------------------------------
template <bool AF32>
__global__ __launch_bounds__(256) void gemm_mfma(
    const void* __restrict__ Ap, const ushort* __restrict__ Bt,
    const float* __restrict__ bias, float* __restrict__ C,
    int M, int N, int K) {
  __shared__ ushort As[128 * 32];
  __shared__ ushort Bs[128 * 32];
  const int tid = threadIdx.x;
  const int m0 = blockIdx.y * 128;
  const int n0 = blockIdx.x * 128;
  const int wave = tid >> 6;
  const int lane = tid & 63;
  const int quad = lane >> 4;
  const int lr = lane & 15;
  const int wm = (wave >> 1) * 64;  // wave row offset in tile
  const int wn = (wave & 1) * 64;   // wave col offset in tile

  f32x4 acc[4][4];
#pragma unroll
  for (int i = 0; i < 4; ++i)
#pragma unroll
    for (int j = 0; j < 4; ++j) acc[i][j] = (f32x4){0.f, 0.f, 0.f, 0.f};

  for (int kt = 0; kt < K; kt += 32) {
    // ---- stage A and B tiles (128 rows x 32 bf16 each) ----
#pragma unroll
    for (int i = 0; i < 2; ++i) {
      const int id = tid + i * 256;  // 0..511 chunk ids (8 bf16 each)
      const int r = id >> 2;         // 0..127
      const int c = id & 3;          // logical chunk 0..3
      const int p = c ^ swz(r);      // swizzled position
      // A chunk
      uint4 apack;
      if (AF32) {
        const float* Af = (const float*)Ap;
        const float* src = &Af[(size_t)(m0 + r) * K + kt + c * 8];
        float4 f0 = *reinterpret_cast<const float4*>(src);
        float4 f1 = *reinterpret_cast<const float4*>(src + 4);
        apack.x = (uint)f2bf(f0.x) | ((uint)f2bf(f0.y) << 16);
        apack.y = (uint)f2bf(f0.z) | ((uint)f2bf(f0.w) << 16);
        apack.z = (uint)f2bf(f1.x) | ((uint)f2bf(f1.y) << 16);
        apack.w = (uint)f2bf(f1.z) | ((uint)f2bf(f1.w) << 16);
      } else {
        const ushort* Ab = (const ushort*)Ap;
        apack = *reinterpret_cast<const uint4*>(
            &Ab[(size_t)(m0 + r) * K + kt + c * 8]);
      }
      *reinterpret_cast<uint4*>(&As[r * 32 + p * 8]) = apack;
      // B chunk
      uint4 bpack = *reinterpret_cast<const uint4*>(
          &Bt[(size_t)(n0 + r) * K + kt + c * 8]);
      *reinterpret_cast<uint4*>(&Bs[r * 32 + p * 8]) = bpack;
    }
    __syncthreads();

    // ---- fragments + MFMA ----
    short8v af[4], bf[4];
#pragma unroll
    for (int x = 0; x < 4; ++x) {
      const int ra = wm + x * 16 + lr;
      af[x] = *reinterpret_cast<const short8v*>(
          &As[ra * 32 + (quad ^ swz(ra)) * 8]);
      const int rb = wn + x * 16 + lr;
      bf[x] = *reinterpret_cast<const short8v*>(
          &Bs[rb * 32 + (quad ^ swz(rb)) * 8]);
    }
#pragma unroll
    for (int i = 0; i < 4; ++i)
#pragma unroll
      for (int j = 0; j < 4; ++j)
        acc[i][j] = __builtin_amdgcn_mfma_f32_16x16x32_bf16(
            af[i], bf[j], acc[i][j], 0, 0, 0);
    __syncthreads();
  }

  // ---- epilogue: D row = quad*4+reg, col = lane&15 (m89-verified) ----
#pragma unroll
  for (int i = 0; i < 4; ++i) {
    const int row_base = m0 + wm + i * 16 + quad * 4;
#pragma unroll
    for (int j = 0; j < 4; ++j) {
      const int col = n0 + wn + j * 16 + lr;
      const float b = bias[col];
#pragma unroll
      for (int rg = 0; rg < 4; ++rg) {
        C[(size_t)(row_base + rg) * N + col] = acc[i][j][rg] + b;
      }
    }
  }
}

// ---------------------------------------------------------------------------
// Flash-style causal GQA attention (fp32 math), bf16 output.
// Grid: (S/64, NH, BATCH). Block: 256 threads.
// LPT: heaviest (largest q0) blocks dispatch first to fix causal imbalance.
// ---------------------------------------------------------------------------
__global__ __launch_bounds__(256, 1) void gqa_attn(
    const float* __restrict__ Q, const float* __restrict__ Kg,
    const float* __restrict__ Vg, ushort* __restrict__ O, int S) {
  __shared__ float Qs[64][128];
  __shared__ float Ks[64][128];
  __shared__ float Vs[64][128];
  __shared__ float Ps[64][68];   // +4 pad -> 2-way-max conflicts on P reads
  __shared__ float red[64][16];
  __shared__ float m_s[64], l_s[64], alpha_s[64];

  const int tid = threadIdx.x;
  const int q0 = ((int)gridDim.x - 1 - (int)blockIdx.x) * 64;  // LPT order
  const int hq = blockIdx.y;
  const int b = blockIdx.z;
  const int kvh = hq >> 2;  // GQ = 4
  const float scale = 0.08838834764831845f;  // 1/sqrt(128)

  const float* Qb = Q + ((size_t)b * S) * (NH * HD) + hq * HD;
  const float* Kb = Kg + ((size_t)b * S) * (NKV * HD) + kvh * HD;
  const float* Vb = Vg + ((size_t)b * S) * (NKV * HD) + kvh * HD;

  const int rg = tid >> 4;  // 0..15: rows rg*4 .. rg*4+3
  const int cg = tid & 15;  // 0..15: cols cg*4 .. cg*4+3 (and d-groups for O)

  // Stage Q tile (swizzled)
#pragma unroll
  for (int i = 0; i < 8; ++i) {
    int idx = tid + i * 256;  // 0..2047 float4 chunks
    int r = idx >> 5;         // row 0..63
    int c = idx & 31;         // chunk 0..31
    int sc = c ^ ((r >> 2) & 7);
    *reinterpret_cast<float4*>(&Qs[r][sc * 4]) =
        *reinterpret_cast<const float4*>(
            &Qb[(size_t)(q0 + r) * (NH * HD) + c * 4]);
  }
  if (tid < 64) {
    m_s[tid] = -INFINITY;
    l_s[tid] = 0.f;
  }
  float Oacc[4][8] = {};  // rows rg*4+i; d = cg*4+dd and 64+cg*4+dd
  __syncthreads();

  const int ntiles = q0 / 64 + 1;  // causal: only tiles with keys <= q0+63
  for (int kt = 0; kt < ntiles; ++kt) {
    const int k0 = kt * 64;
    // Stage K and V tiles (swizzled)
#pragma unroll
    for (int i = 0; i < 8; ++i) {
      int idx = tid + i * 256;
      int r = idx >> 5;
      int c = idx & 31;
      int sc = c ^ ((r >> 2) & 7);
      *reinterpret_cast<float4*>(&Ks[r][sc * 4]) =
          *reinterpret_cast<const float4*>(
              &Kb[(size_t)(k0 + r) * (NKV * HD) + c * 4]);
      *reinterpret_cast<float4*>(&Vs[r][sc * 4]) =
          *reinterpret_cast<const float4*>(
              &Vb[(size_t)(k0 + r) * (NKV * HD) + c * 4]);
    }
    __syncthreads();

    // ---- scores: 4x4 per thread over d=128 (unroll 4: no spill) ----
    float s[4][4] = {};
#pragma unroll 4
    for (int c = 0; c < 32; ++c) {
      const int qsc = (c ^ (rg & 7)) * 4;  // (row>>2)&7 == rg&7
      const int ksc = (c ^ (cg & 7)) * 4;  // (col>>2)&7 == cg&7
      float4 qv[4], kv[4];
#pragma unroll
      for (int i = 0; i < 4; ++i)
        qv[i] = *reinterpret_cast<const float4*>(&Qs[rg * 4 + i][qsc]);
#pragma unroll
      for (int j = 0; j < 4; ++j)
        kv[j] = *reinterpret_cast<const float4*>(&Ks[cg * 4 + j][ksc]);
#pragma unroll
      for (int i = 0; i < 4; ++i)
#pragma unroll
        for (int j = 0; j < 4; ++j)
          s[i][j] += qv[i].x * kv[j].x + qv[i].y * kv[j].y +
                     qv[i].z * kv[j].z + qv[i].w * kv[j].w;
    }

    // ---- scale + causal mask + partial row max ----
#pragma unroll
    for (int i = 0; i < 4; ++i) {
      const int qi = q0 + rg * 4 + i;
      float mx = -INFINITY;
#pragma unroll
      for (int j = 0; j < 4; ++j) {
        const int kj = k0 + cg * 4 + j;
        s[i][j] = (kj <= qi) ? s[i][j] * scale : -INFINITY;
        mx = fmaxf(mx, s[i][j]);
      }
      red[rg * 4 + i][cg] = mx;
    }
    __syncthreads();
    if (tid < 64) {
      float mx = red[tid][0];
#pragma unroll
      for (int c2 = 1; c2 < 16; ++c2) mx = fmaxf(mx, red[tid][c2]);
      const float m_new = fmaxf(m_s[tid], mx);
      alpha_s[tid] = __expf(m_s[tid] - m_new);
      m_s[tid] = m_new;
    }
    __syncthreads();

    // ---- P = exp(s - m), partial row sums, rescale O ----
#pragma unroll
    for (int i = 0; i < 4; ++i) {
      const int r = rg * 4 + i;
      const float m = m_s[r];
      float sum = 0.f;
#pragma unroll
      for (int j = 0; j < 4; ++j) {
        const float p = __expf(s[i][j] - m);
        Ps[r][cg * 4 + j] = p;
        sum += p;
      }
      red[r][cg] = sum;
      const float a = alpha_s[r];
#pragma unroll
      for (int dd = 0; dd < 8; ++dd) Oacc[i][dd] *= a;
    }
    __syncthreads();
    if (tid < 64) {
      float sum = 0.f;
#pragma unroll
      for (int c2 = 0; c2 < 16; ++c2) sum += red[tid][c2];
      l_s[tid] = l_s[tid] * alpha_s[tid] + sum;
    }

    // ---- O += P @ V (unroll 2: no spill) ----
#pragma unroll 2
    for (int jc = 0; jc < 16; ++jc) {
      const int jj0 = jc * 4;
      float4 pv[4];
#pragma unroll
      for (int i = 0; i < 4; ++i)
        pv[i] = *reinterpret_cast<const float4*>(&Ps[rg * 4 + i][jj0]);
#pragma unroll
      for (int j = 0; j < 4; ++j) {
        const int vr = jj0 + j;
        const int sw = (vr >> 2) & 7;
        float4 v1 = *reinterpret_cast<const float4*>(&Vs[vr][(cg ^ sw) * 4]);
        float4 v2 =
            *reinterpret_cast<const float4*>(&Vs[vr][((cg + 16) ^ sw) * 4]);
#pragma unroll
        for (int i = 0; i < 4; ++i) {
          const float p = reinterpret_cast<const float*>(&pv[i])[j];
          Oacc[i][0] += p * v1.x;
          Oacc[i][1] += p * v1.y;
          Oacc[i][2] += p * v1.z;
          Oacc[i][3] += p * v1.w;
          Oacc[i][4] += p * v2.x;
          Oacc[i][5] += p * v2.y;
          Oacc[i][6] += p * v2.z;
          Oacc[i][7] += p * v2.w;
        }
      }
    }
    __syncthreads();  // protect Ks/Vs/Ps/red for next tile; l_s for epilogue
  }

  // ---- epilogue: O / l, written as bf16 (feeds out-proj MFMA GEMM) ----
  ushort* Ob = O + ((size_t)b * S) * (NH * HD) + hq * HD;
#pragma unroll
  for (int i = 0; i < 4; ++i) {
    const int r = rg * 4 + i;
    const float inv = 1.0f / l_s[r];
    ushort4 o1, o2;
    o1.x = f2bf(Oacc[i][0] * inv);
    o1.y = f2bf(Oacc[i][1] * inv);
    o1.z = f2bf(Oacc[i][2] * inv);
    o1.w = f2bf(Oacc[i][3] * inv);
    o2.x = f2bf(Oacc[i][4] * inv);
    o2.y = f2bf(Oacc[i][5] * inv);
    o2.z = f2bf(Oacc[i][6] * inv);
    o2.w = f2bf(Oacc[i][7] * inv);
    *reinterpret_cast<ushort4*>(
        &Ob[(size_t)(q0 + r) * (NH * HD) + cg * 4]) = o1;
    *reinterpret_cast<ushort4*>(
        &Ob[(size_t)(q0 + r) * (NH * HD) + 64 + cg * 4]) = o2;
  }
}

// ---------------------------------------------------------------------------
extern "C" void kernel_launch(void* const* d_in, const int* in_sizes, int n_in,
                              void* d_out, int out_size, void* d_ws,
                              size_t ws_size, hipStream_t stream) {
  const float* x = (const float*)d_in[0];
  const float* wq = (const float*)d_in[1];
  const float* bq = (const float*)d_in[2];
  const float* wk = (const float*)d_in[3];
  const float* bk = (const float*)d_in[4];
  const float* wv = (const float*)d_in[5];
  const float* bv = (const float*)d_in[6];
  const float* wo = (const float*)d_in[7];
  const float* bo = (const float*)d_in[8];
  float* out = (float*)d_out;

  const int M = in_sizes[0] / HID;  // B*S = 4096
  const int S = M / BATCH;          // 2048

  // Workspace layout (72 MB total; attnb reuses the wq/wk/wv transpose
  // region, which is dead once the q/k/v GEMMs complete):
  char* w = (char*)d_ws;
  float* q = (float*)(w + 0);                       // 32 MB fp32
  float* k = (float*)(w + (32u << 20));             //  8 MB fp32
  float* v = (float*)(w + (40u << 20));             //  8 MB fp32
  ushort* woT = (ushort*)(w + (48u << 20));         //  8 MB bf16 [2048][2048]
  ushort* wqT = (ushort*)(w + (56u << 20));         //  8 MB bf16 [2048][2048]
  ushort* wkT = (ushort*)(w + (64u << 20));         //  2 MB bf16 [512][2048]
  ushort* wvT = (ushort*)(w + (66u << 20));         //  2 MB bf16 [512][2048]
  ushort* attnb = (ushort*)(w + (56u << 20));       // 16 MB bf16 (aliases wqT+)

  dim3 blk(256);
  // Weight transpose-casts: fp32 [K][N] -> bf16 [N][K]
  tcast_kernel<<<dim3(HID / 32, (NH * HD) / 32), blk, 0, stream>>>(
      wq, wqT, HID, NH * HD);
  tcast_kernel<<<dim3(HID / 32, (NKV * HD) / 32), blk, 0, stream>>>(
      wk, wkT, HID, NKV * HD);
  tcast_kernel<<<dim3(HID / 32, (NKV * HD) / 32), blk, 0, stream>>>(
      wv, wvT, HID, NKV * HD);
  tcast_kernel<<<dim3(HID / 32, HID / 32), blk, 0, stream>>>(
      wo, woT, HID, HID);

  // Projections (bf16 MFMA, A = x fp32 converted in staging)
  gemm_mfma<true><<<dim3((NH * HD) / 128, M / 128), blk, 0, stream>>>(
      x, wqT, bq, q, M, NH * HD, HID);
  gemm_mfma<true><<<dim3((NKV * HD) / 128, M / 128), blk, 0, stream>>>(
      x, wkT, bk, k, M, NKV * HD, HID);
  gemm_mfma<true><<<dim3((NKV * HD) / 128, M / 128), blk, 0, stream>>>(
      x, wvT, bv, v, M, NKV * HD, HID);

  // Attention (fp32 math, bf16 output)
  gqa_attn<<<dim3(S / 64, NH, BATCH), blk, 0, stream>>>(q, k, v, attnb, S);

  // Output projection (A = attnb bf16)
  gemm_mfma<false><<<dim3(HID / 128, M / 128), blk, 0, stream>>>(
      attnb, woT, bo, out, M, HID, HID);
}

// Round 7
// 559.463 us; speedup vs baseline: 18.4211x; 3.1603x over previous
//
#include <hip/hip_runtime.h>
#include <hip/hip_bf16.h>
#include <math.h>

// Problem constants (GQA attention block)
#define HID 2048
#define NH 16      // num query heads
#define NKV 4      // kv heads
#define HD 128     // head dim
#define GQ 4       // heads per kv group
#define BATCH 2

typedef short short8v __attribute__((ext_vector_type(8)));
typedef float f32x4 __attribute__((ext_vector_type(4)));

// fp32 -> bf16 round-to-nearest-even
__device__ __forceinline__ ushort f2bf(float f) {
  uint u = __float_as_uint(f);
  uint r = (u + 0x7fffu + ((u >> 16) & 1u)) >> 16;
  return (ushort)r;
}

// GEMM LDS swizzle (4 chunks of 8 bf16 per 32-elem row)
__device__ __forceinline__ int swz(int r) {
  return (r & 3) ^ ((r >> 2) & 3);
}

// ---------------------------------------------------------------------------
// Transpose-cast: W fp32 [K][N] -> Wt bf16 [N][K]. 32x32 tiles via LDS.
// ---------------------------------------------------------------------------
__global__ __launch_bounds__(256) void tcast_kernel(
    const float* __restrict__ W, ushort* __restrict__ Wt, int K, int N) {
  __shared__ float T[32][33];
  const int k0 = blockIdx.x * 32;
  const int n0 = blockIdx.y * 32;
  const int t = threadIdx.x;
  const int r = t >> 3;          // 0..31
  const int c4 = (t & 7) * 4;    // 0..28
  float4 vin = *reinterpret_cast<const float4*>(
      &W[(size_t)(k0 + r) * N + n0 + c4]);
  T[c4 + 0][r] = vin.x;
  T[c4 + 1][r] = vin.y;
  T[c4 + 2][r] = vin.z;
  T[c4 + 3][r] = vin.w;
  __syncthreads();
  ushort4 o;
  o.x = f2bf(T[r][c4 + 0]);
  o.y = f2bf(T[r][c4 + 1]);
  o.z = f2bf(T[r][c4 + 2]);
  o.w = f2bf(T[r][c4 + 3]);
  *reinterpret_cast<ushort4*>(&Wt[(size_t)(n0 + r) * K + k0 + c4]) = o;
}

// ---------------------------------------------------------------------------
// bf16 MFMA GEMM: C[M,N] = A[M,K] * Bt[N,K]^T + bias.
// AF32: A fp32 (converted in staging) else bf16.
// OMODE 0: C fp32 [M][N].  OMODE 1: C bf16 [M][N].
// OMODE 2: C bf16 transposed per-kv-head: vT[b][kvh][d][sdim], col=kvh*128+d,
//          row=b*sdim+s (feeds PV MFMA B-operand).
// ---------------------------------------------------------------------------
template <bool AF32, int OMODE>
__global__ __launch_bounds__(256) void gemm_mfma(
    const void* __restrict__ Ap, const ushort* __restrict__ Bt,
    const float* __restrict__ bias, void* __restrict__ Cp,
    int M, int N, int K, int sdim) {
  __shared__ ushort As[128 * 32];
  __shared__ ushort Bs[128 * 32];
  const int tid = threadIdx.x;
  const int m0 = blockIdx.y * 128;
  const int n0 = blockIdx.x * 128;
  const int wave = tid >> 6;
  const int lane = tid & 63;
  const int quad = lane >> 4;
  const int lr = lane & 15;
  const int wm = (wave >> 1) * 64;
  const int wn = (wave & 1) * 64;

  f32x4 acc[4][4];
#pragma unroll
  for (int i = 0; i < 4; ++i)
#pragma unroll
    for (int j = 0; j < 4; ++j) acc[i][j] = (f32x4){0.f, 0.f, 0.f, 0.f};

  for (int kt = 0; kt < K; kt += 32) {
#pragma unroll
    for (int i = 0; i < 2; ++i) {
      const int id = tid + i * 256;
      const int r = id >> 2;
      const int c = id & 3;
      const int p = c ^ swz(r);
      uint4 apack;
      if (AF32) {
        const float* Af = (const float*)Ap;
        const float* src = &Af[(size_t)(m0 + r) * K + kt + c * 8];
        float4 f0 = *reinterpret_cast<const float4*>(src);
        float4 f1 = *reinterpret_cast<const float4*>(src + 4);
        apack.x = (uint)f2bf(f0.x) | ((uint)f2bf(f0.y) << 16);
        apack.y = (uint)f2bf(f0.z) | ((uint)f2bf(f0.w) << 16);
        apack.z = (uint)f2bf(f1.x) | ((uint)f2bf(f1.y) << 16);
        apack.w = (uint)f2bf(f1.z) | ((uint)f2bf(f1.w) << 16);
      } else {
        const ushort* Ab = (const ushort*)Ap;
        apack = *reinterpret_cast<const uint4*>(
            &Ab[(size_t)(m0 + r) * K + kt + c * 8]);
      }
      *reinterpret_cast<uint4*>(&As[r * 32 + p * 8]) = apack;
      uint4 bpack = *reinterpret_cast<const uint4*>(
          &Bt[(size_t)(n0 + r) * K + kt + c * 8]);
      *reinterpret_cast<uint4*>(&Bs[r * 32 + p * 8]) = bpack;
    }
    __syncthreads();

    short8v af[4], bf[4];
#pragma unroll
    for (int x = 0; x < 4; ++x) {
      const int ra = wm + x * 16 + lr;
      af[x] = *reinterpret_cast<const short8v*>(
          &As[ra * 32 + (quad ^ swz(ra)) * 8]);
      const int rb = wn + x * 16 + lr;
      bf[x] = *reinterpret_cast<const short8v*>(
          &Bs[rb * 32 + (quad ^ swz(rb)) * 8]);
    }
#pragma unroll
    for (int i = 0; i < 4; ++i)
#pragma unroll
      for (int j = 0; j < 4; ++j)
        acc[i][j] = __builtin_amdgcn_mfma_f32_16x16x32_bf16(
            af[i], bf[j], acc[i][j], 0, 0, 0);
    __syncthreads();
  }

  // D layout: row = quad*4+reg, col = lane&15 (verified via R5 output)
#pragma unroll
  for (int i = 0; i < 4; ++i) {
    const int row_base = m0 + wm + i * 16 + quad * 4;
#pragma unroll
    for (int j = 0; j < 4; ++j) {
      const int col = n0 + wn + j * 16 + lr;
      const float b = bias[col];
      if (OMODE == 0) {
        float* C = (float*)Cp;
#pragma unroll
        for (int rg = 0; rg < 4; ++rg)
          C[(size_t)(row_base + rg) * N + col] = acc[i][j][rg] + b;
      } else if (OMODE == 1) {
        ushort* C = (ushort*)Cp;
#pragma unroll
        for (int rg = 0; rg < 4; ++rg)
          C[(size_t)(row_base + rg) * N + col] = f2bf(acc[i][j][rg] + b);
      } else {
        ushort* C = (ushort*)Cp;
        const int bb = (row_base >= sdim) ? 1 : 0;
        const int s = row_base - bb * sdim;
        const int kvh = col >> 7;
        const int d = col & 127;
        ushort4 o;
        o.x = f2bf(acc[i][j][0] + b);
        o.y = f2bf(acc[i][j][1] + b);
        o.z = f2bf(acc[i][j][2] + b);
        o.w = f2bf(acc[i][j][3] + b);
        *reinterpret_cast<ushort4*>(
            &C[((size_t)(bb * NKV + kvh) * HD + d) * sdim + s]) = o;
      }
    }
  }
}

// ---------------------------------------------------------------------------
// MFMA flash attention (causal GQA), all-bf16 inputs, bf16 output.
// Grid: (S/64, NH, BATCH), 256 threads = 4 waves; wave w owns Q rows
// [w*16, w*16+16).
// R6 bug: the P->LDS->A-frag and epilogue LDS round-trips had NO barrier
// between ushort stores and short8v/uint4 loads. Different TBAA classes
// (ushort vs int) let the compiler reorder the ds_read before the ds_write
// -> stale LDS -> O(1) corruption (absmax 1.355). __syncthreads() between
// write and read is a compiler memory fence + hardware barrier: fixes both.
// ---------------------------------------------------------------------------
__global__ __launch_bounds__(256, 2) void gqa_attn_mfma(
    const ushort* __restrict__ Qg, const ushort* __restrict__ Kgl,
    const ushort* __restrict__ Vt_g, ushort* __restrict__ O, int S) {
  __shared__ ushort Qs[64 * 128];   // chunk c of row r at c^(r&15)
  __shared__ ushort Ks[64 * 128];   // same swizzle
  __shared__ ushort Vs[128 * 64];   // V^T: chunk c of row d at c^(d&7)
  __shared__ ushort Ps[4][16][72];  // per-wave P, +8 pad

  const int tid = threadIdx.x;
  const int wave = tid >> 6;
  const int lane = tid & 63;
  const int quad = lane >> 4;
  const int lr = lane & 15;
  const int q0 = ((int)gridDim.x - 1 - (int)blockIdx.x) * 64;  // LPT
  const int hq = blockIdx.y;
  const int b = blockIdx.z;
  const int kvh = hq >> 2;
  const float scale = 0.08838834764831845f;  // 1/sqrt(128)

  const ushort* Qb = Qg + ((size_t)b * S) * (NH * HD) + (size_t)hq * HD;
  const ushort* Kb = Kgl + ((size_t)b * S) * (NKV * HD) + (size_t)kvh * HD;
  const ushort* Vb = Vt_g + ((size_t)(b * NKV + kvh) * HD) * S;

  // Stage Q tile (64 rows x 16 chunks)
#pragma unroll
  for (int i = 0; i < 4; ++i) {
    const int id = tid + i * 256;
    const int r = id >> 4, c = id & 15;
    const int p = c ^ (r & 15);
    *reinterpret_cast<uint4*>(&Qs[r * 128 + p * 8]) =
        *reinterpret_cast<const uint4*>(
            &Qb[(size_t)(q0 + r) * (NH * HD) + c * 8]);
  }

  f32x4 oacc[8];
#pragma unroll
  for (int nb = 0; nb < 8; ++nb) oacc[nb] = (f32x4){0.f, 0.f, 0.f, 0.f};
  float m_r[4] = {-INFINITY, -INFINITY, -INFINITY, -INFINITY};
  float l_r[4] = {0.f, 0.f, 0.f, 0.f};

  const int ntiles = q0 / 64 + 1;
  for (int kt = 0; kt < ntiles; ++kt) {
    const int k0 = kt * 64;
    __syncthreads();  // prior tile's reads done (and Q staging on iter 0)
    // stage K tile
#pragma unroll
    for (int i = 0; i < 4; ++i) {
      const int id = tid + i * 256;
      const int r = id >> 4, c = id & 15;
      const int p = c ^ (r & 15);
      *reinterpret_cast<uint4*>(&Ks[r * 128 + p * 8]) =
          *reinterpret_cast<const uint4*>(
              &Kb[(size_t)(k0 + r) * (NKV * HD) + c * 8]);
    }
    // stage V^T tile (128 d-rows x 8 chunks of 8 keys)
#pragma unroll
    for (int i = 0; i < 4; ++i) {
      const int id = tid + i * 256;
      const int d = id >> 3, c = id & 7;
      const int p = c ^ (d & 7);
      *reinterpret_cast<uint4*>(&Vs[d * 64 + p * 8]) =
          *reinterpret_cast<const uint4*>(&Vb[(size_t)d * S + k0 + c * 8]);
    }
    __syncthreads();

    // ---- QK^T: wave band 16 q-rows x 64 keys ----
    short8v aq[4];
#pragma unroll
    for (int ks = 0; ks < 4; ++ks) {
      const int ra = wave * 16 + lr;
      aq[ks] = *reinterpret_cast<const short8v*>(
          &Qs[ra * 128 + (((ks * 4 + quad) ^ lr) & 15) * 8]);
    }
    f32x4 sacc[4];
#pragma unroll
    for (int nb = 0; nb < 4; ++nb) {
      sacc[nb] = (f32x4){0.f, 0.f, 0.f, 0.f};
      const int rb = nb * 16 + lr;
#pragma unroll
      for (int ks = 0; ks < 4; ++ks) {
        short8v bk = *reinterpret_cast<const short8v*>(
            &Ks[rb * 128 + (((ks * 4 + quad) ^ lr) & 15) * 8]);
        sacc[nb] = __builtin_amdgcn_mfma_f32_16x16x32_bf16(
            aq[ks], bk, sacc[nb], 0, 0, 0);
      }
    }

    // ---- register softmax (rows = quad*4+rg; 16-lane shfl reduce) ----
    const bool diag = (kt == ntiles - 1);
    float pmat[4][4];
    float alpha[4];
#pragma unroll
    for (int rg = 0; rg < 4; ++rg) {
      float mx = -INFINITY;
#pragma unroll
      for (int nb = 0; nb < 4; ++nb) {
        float sv = sacc[nb][rg] * scale;
        if (diag) {
          const int kj = k0 + nb * 16 + lr;
          const int qi = q0 + wave * 16 + quad * 4 + rg;
          if (kj > qi) sv = -1e30f;
        }
        pmat[nb][rg] = sv;
        mx = fmaxf(mx, sv);
      }
      mx = fmaxf(mx, __shfl_xor(mx, 1));
      mx = fmaxf(mx, __shfl_xor(mx, 2));
      mx = fmaxf(mx, __shfl_xor(mx, 4));
      mx = fmaxf(mx, __shfl_xor(mx, 8));
      const float mn = fmaxf(m_r[rg], mx);
      alpha[rg] = __expf(m_r[rg] - mn);
      m_r[rg] = mn;
      float rs = 0.f;
#pragma unroll
      for (int nb = 0; nb < 4; ++nb) {
        const float p = __expf(pmat[nb][rg] - mn);
        pmat[nb][rg] = p;
        rs += p;
      }
      rs += __shfl_xor(rs, 1);
      rs += __shfl_xor(rs, 2);
      rs += __shfl_xor(rs, 4);
      rs += __shfl_xor(rs, 8);
      l_r[rg] = l_r[rg] * alpha[rg] + rs;
    }

    // P -> LDS (D-layout write, A-layout read)
#pragma unroll
    for (int rg = 0; rg < 4; ++rg)
#pragma unroll
      for (int nb = 0; nb < 4; ++nb)
        Ps[wave][quad * 4 + rg][nb * 16 + lr] = f2bf(pmat[nb][rg]);

    // rescale O while the P stores land
#pragma unroll
    for (int nb = 0; nb < 8; ++nb)
#pragma unroll
      for (int rg = 0; rg < 4; ++rg) oacc[nb][rg] *= alpha[rg];

    __syncthreads();  // fence: P stores (ushort) -> A-frag loads (short8v)

    // ---- PV: O[16 x 128] += P[16 x 64] @ V[64 x 128] ----
    short8v ap[2];
#pragma unroll
    for (int ks = 0; ks < 2; ++ks)
      ap[ks] = *reinterpret_cast<const short8v*>(
          &Ps[wave][lr][ks * 32 + quad * 8]);
#pragma unroll
    for (int nb = 0; nb < 8; ++nb) {
      const int rv = nb * 16 + lr;
#pragma unroll
      for (int ks = 0; ks < 2; ++ks) {
        short8v bv = *reinterpret_cast<const short8v*>(
            &Vs[rv * 64 + (((ks * 4 + quad) ^ lr) & 7) * 8]);
        oacc[nb] = __builtin_amdgcn_mfma_f32_16x16x32_bf16(
            ap[ks], bv, oacc[nb], 0, 0, 0);
      }
    }
  }

  // ---- epilogue: O/l -> bf16, bounce through Qs for coalesced stores ----
  __syncthreads();  // all tile reads done; Qs reusable
  float inv[4];
#pragma unroll
  for (int rg = 0; rg < 4; ++rg) inv[rg] = 1.0f / l_r[rg];
  ushort* ow = &Qs[wave * 16 * 128];
#pragma unroll
  for (int nb = 0; nb < 8; ++nb)
#pragma unroll
    for (int rg = 0; rg < 4; ++rg)
      ow[(quad * 4 + rg) * 128 + nb * 16 + lr] = f2bf(oacc[nb][rg] * inv[rg]);
  __syncthreads();  // fence: ushort stores -> uint4 loads (TBAA reorder fix)
  ushort* Ob = O + ((size_t)b * S) * (NH * HD) + (size_t)hq * HD;
#pragma unroll
  for (int ii = 0; ii < 4; ++ii) {
    const int id = lane + ii * 64;
    const int r16 = id >> 4, c = id & 15;
    uint4 val = *reinterpret_cast<const uint4*>(&ow[r16 * 128 + c * 8]);
    *reinterpret_cast<uint4*>(
        &Ob[(size_t)(q0 + wave * 16 + r16) * (NH * HD) + c * 8]) = val;
  }
}

// ---------------------------------------------------------------------------
extern "C" void kernel_launch(void* const* d_in, const int* in_sizes, int n_in,
                              void* d_out, int out_size, void* d_ws,
                              size_t ws_size, hipStream_t stream) {
  const float* x = (const float*)d_in[0];
  const float* wq = (const float*)d_in[1];
  const float* bq = (const float*)d_in[2];
  const float* wk = (const float*)d_in[3];
  const float* bk = (const float*)d_in[4];
  const float* wv = (const float*)d_in[5];
  const float* bv = (const float*)d_in[6];
  const float* wo = (const float*)d_in[7];
  const float* bo = (const float*)d_in[8];
  float* out = (float*)d_out;

  const int M = in_sizes[0] / HID;  // B*S = 4096
  const int S = M / BATCH;          // 2048

  // Workspace (60 MB total)
  char* w = (char*)d_ws;
  ushort* qb    = (ushort*)(w + 0);            // 16 MB bf16 [M][2048]
  ushort* kb    = (ushort*)(w + (16u << 20));  //  4 MB bf16 [M][512]
  ushort* vT    = (ushort*)(w + (20u << 20));  //  4 MB bf16 [B][NKV][HD][S]
  ushort* attnb = (ushort*)(w + (24u << 20));  // 16 MB bf16 [M][2048]
  ushort* wqT   = (ushort*)(w + (40u << 20));  //  8 MB bf16 [2048][2048]
  ushort* wkT   = (ushort*)(w + (48u << 20));  //  2 MB bf16 [512][2048]
  ushort* wvT   = (ushort*)(w + (50u << 20));  //  2 MB bf16 [512][2048]
  ushort* woT   = (ushort*)(w + (52u << 20));  //  8 MB bf16 [2048][2048]

  dim3 blk(256);
  // Weight transpose-casts
  tcast_kernel<<<dim3(HID / 32, (NH * HD) / 32), blk, 0, stream>>>(
      wq, wqT, HID, NH * HD);
  tcast_kernel<<<dim3(HID / 32, (NKV * HD) / 32), blk, 0, stream>>>(
      wk, wkT, HID, NKV * HD);
  tcast_kernel<<<dim3(HID / 32, (NKV * HD) / 32), blk, 0, stream>>>(
      wv, wvT, HID, NKV * HD);
  tcast_kernel<<<dim3(HID / 32, HID / 32), blk, 0, stream>>>(
      wo, woT, HID, HID);

  // Projections -> bf16 (v transposed per kv-head)
  gemm_mfma<true, 1><<<dim3((NH * HD) / 128, M / 128), blk, 0, stream>>>(
      x, wqT, bq, qb, M, NH * HD, HID, S);
  gemm_mfma<true, 1><<<dim3((NKV * HD) / 128, M / 128), blk, 0, stream>>>(
      x, wkT, bk, kb, M, NKV * HD, HID, S);
  gemm_mfma<true, 2><<<dim3((NKV * HD) / 128, M / 128), blk, 0, stream>>>(
      x, wvT, bv, vT, M, NKV * HD, HID, S);

  // MFMA flash attention
  gqa_attn_mfma<<<dim3(S / 64, NH, BATCH), blk, 0, stream>>>(
      qb, kb, vT, attnb, S);

  // Output projection (fp32 out)
  gemm_mfma<false, 0><<<dim3(HID / 128, M / 128), blk, 0, stream>>>(
      attnb, woT, bo, out, M, HID, HID, S);
}

// Round 8
// 419.288 us; speedup vs baseline: 24.5796x; 1.3343x over previous
//
#include <hip/hip_runtime.h>
#include <hip/hip_bf16.h>
#include <math.h>

// Problem constants (GQA attention block)
#define HID 2048
#define NH 16      // num query heads
#define NKV 4      // kv heads
#define HD 128     // head dim
#define GQ 4       // heads per kv group
#define BATCH 2

typedef short short8v __attribute__((ext_vector_type(8)));
typedef float f32x4 __attribute__((ext_vector_type(4)));

// fp32 -> bf16 round-to-nearest-even
__device__ __forceinline__ ushort f2bf(float f) {
  uint u = __float_as_uint(f);
  uint r = (u + 0x7fffu + ((u >> 16) & 1u)) >> 16;
  return (ushort)r;
}

// Async global->LDS DMA, 16 B per lane. LDS dest = wave-uniform base +
// lane*16 (hardware rule). C-style casts emit addrspacecast (flat->AS1/AS3).
__device__ __forceinline__ void gld_lds16(const void* g, void* lds) {
  __builtin_amdgcn_global_load_lds(
      (const __attribute__((address_space(1))) unsigned int*)g,
      (__attribute__((address_space(3))) unsigned int*)lds, 16, 0, 0);
}

// ---------------------------------------------------------------------------
// x fp32 -> bf16, 8 elems/thread
// ---------------------------------------------------------------------------
__global__ __launch_bounds__(256) void castx_kernel(
    const float* __restrict__ x, ushort* __restrict__ xb) {
  const int i = ((int)blockIdx.x * 256 + (int)threadIdx.x) * 8;
  float4 f0 = *reinterpret_cast<const float4*>(x + i);
  float4 f1 = *reinterpret_cast<const float4*>(x + i + 4);
  uint4 o;
  o.x = (uint)f2bf(f0.x) | ((uint)f2bf(f0.y) << 16);
  o.y = (uint)f2bf(f0.z) | ((uint)f2bf(f0.w) << 16);
  o.z = (uint)f2bf(f1.x) | ((uint)f2bf(f1.y) << 16);
  o.w = (uint)f2bf(f1.z) | ((uint)f2bf(f1.w) << 16);
  *reinterpret_cast<uint4*>(xb + i) = o;
}

// ---------------------------------------------------------------------------
// Transpose-cast: W fp32 [K][N] -> Wt bf16 [N][K]. 32x32 tiles via LDS.
// ---------------------------------------------------------------------------
__global__ __launch_bounds__(256) void tcast_kernel(
    const float* __restrict__ W, ushort* __restrict__ Wt, int K, int N) {
  __shared__ float T[32][33];
  const int k0 = blockIdx.x * 32;
  const int n0 = blockIdx.y * 32;
  const int t = threadIdx.x;
  const int r = t >> 3;          // 0..31
  const int c4 = (t & 7) * 4;    // 0..28
  float4 vin = *reinterpret_cast<const float4*>(
      &W[(size_t)(k0 + r) * N + n0 + c4]);
  T[c4 + 0][r] = vin.x;
  T[c4 + 1][r] = vin.y;
  T[c4 + 2][r] = vin.z;
  T[c4 + 3][r] = vin.w;
  __syncthreads();
  ushort4 o;
  o.x = f2bf(T[r][c4 + 0]);
  o.y = f2bf(T[r][c4 + 1]);
  o.z = f2bf(T[r][c4 + 2]);
  o.w = f2bf(T[r][c4 + 3]);
  *reinterpret_cast<ushort4*>(&Wt[(size_t)(n0 + r) * K + k0 + c4]) = o;
}

// ---------------------------------------------------------------------------
// bf16 MFMA GEMM, global_load_lds staging, 128x128 tile, BK=32, 4 waves.
// MODE 0: out-proj. A=attnb, W0=woT, C0=fp32 out [M][2048].
// MODE 1: fused QKV. grid.x spans 3072 cols = [wq:2048 | wk:512 | wv:512];
//         per-segment epilogue: qb bf16 [M][2048], kb bf16 [M][512],
//         vT bf16 [b][kvh][d][S] (PV B-operand layout).
// LDS linear (no swizzle: DMA lane order fixes layout; frag ds_read_b128
// at 64 B row stride covers all 32 banks evenly -> bandwidth-optimal).
// ---------------------------------------------------------------------------
template <int MODE>
__global__ __launch_bounds__(256) void gemm_big(
    const ushort* __restrict__ A,
    const ushort* __restrict__ W0, const ushort* __restrict__ W1,
    const ushort* __restrict__ W2,
    const float* __restrict__ b0, const float* __restrict__ b1,
    const float* __restrict__ b2,
    void* __restrict__ C0, void* __restrict__ C1, void* __restrict__ C2,
    int M, int K, int S) {
  __shared__ ushort As[128 * 32];
  __shared__ ushort Bs[128 * 32];
  const int tid = threadIdx.x;
  const int m0 = blockIdx.y * 128;
  const int n0 = blockIdx.x * 128;
  const int wave = tid >> 6;
  const int lane = tid & 63;
  const int quad = lane >> 4;
  const int lr = lane & 15;
  const int l4 = lane >> 2;       // 0..15: row within 16-row DMA group
  const int lc = (lane & 3) * 8;  // 0,8,16,24: bf16 col offset
  const int wm = (wave >> 1) * 64;
  const int wn = (wave & 1) * 64;

  // segment select (wave-uniform)
  const ushort* Wt;
  const float* bias;
  int nloc, Nout, om;
  void* Cout;
  if (MODE == 0) {
    Wt = W0; bias = b0; nloc = n0; Nout = 2048; om = 0; Cout = C0;
  } else {
    if (n0 < 2048)      { Wt = W0; bias = b0; nloc = n0;        Nout = 2048; om = 1; Cout = C0; }
    else if (n0 < 2560) { Wt = W1; bias = b1; nloc = n0 - 2048; Nout = 512;  om = 1; Cout = C1; }
    else                { Wt = W2; bias = b2; nloc = n0 - 2560; Nout = 512;  om = 2; Cout = C2; }
  }

  f32x4 acc[4][4];
#pragma unroll
  for (int i = 0; i < 4; ++i)
#pragma unroll
    for (int j = 0; j < 4; ++j) acc[i][j] = (f32x4){0.f, 0.f, 0.f, 0.f};

  for (int kt = 0; kt < K; kt += 32) {
    // stage A and B tiles: each wave DMAs 32 rows of each (2 calls x 16 rows)
#pragma unroll
    for (int c = 0; c < 2; ++c) {
      const int r = wave * 32 + c * 16;
      gld_lds16(&A[(size_t)(m0 + r + l4) * K + kt + lc], &As[r * 32]);
      gld_lds16(&Wt[(size_t)(nloc + r + l4) * K + kt + lc], &Bs[r * 32]);
    }
    __syncthreads();  // drains vmcnt (DMA) before reads

    short8v af[4], bf[4];
#pragma unroll
    for (int x = 0; x < 4; ++x) {
      const int ra = wm + x * 16 + lr;
      af[x] = *reinterpret_cast<const short8v*>(&As[ra * 32 + quad * 8]);
      const int rb = wn + x * 16 + lr;
      bf[x] = *reinterpret_cast<const short8v*>(&Bs[rb * 32 + quad * 8]);
    }
#pragma unroll
    for (int i = 0; i < 4; ++i)
#pragma unroll
      for (int j = 0; j < 4; ++j)
        acc[i][j] = __builtin_amdgcn_mfma_f32_16x16x32_bf16(
            af[i], bf[j], acc[i][j], 0, 0, 0);
    __syncthreads();  // reads done before next tile's DMA
  }

  // D layout: row = quad*4+reg, col = lane&15 (verified R5 via output)
#pragma unroll
  for (int i = 0; i < 4; ++i) {
    const int row_base = m0 + wm + i * 16 + quad * 4;
#pragma unroll
    for (int j = 0; j < 4; ++j) {
      const int col = nloc + wn + j * 16 + lr;
      const float b = bias[col];
      if (om == 0) {
        float* C = (float*)Cout;
#pragma unroll
        for (int rg = 0; rg < 4; ++rg)
          C[(size_t)(row_base + rg) * Nout + col] = acc[i][j][rg] + b;
      } else if (om == 1) {
        ushort* C = (ushort*)Cout;
#pragma unroll
        for (int rg = 0; rg < 4; ++rg)
          C[(size_t)(row_base + rg) * Nout + col] = f2bf(acc[i][j][rg] + b);
      } else {
        ushort* C = (ushort*)Cout;
        const int bb = (row_base >= S) ? 1 : 0;
        const int s = row_base - bb * S;
        const int kvh = col >> 7;
        const int d = col & 127;
        ushort4 o;
        o.x = f2bf(acc[i][j][0] + b);
        o.y = f2bf(acc[i][j][1] + b);
        o.z = f2bf(acc[i][j][2] + b);
        o.w = f2bf(acc[i][j][3] + b);
        *reinterpret_cast<ushort4*>(
            &C[((size_t)(bb * NKV + kvh) * HD + d) * S + s]) = o;
      }
    }
  }
}

// ---------------------------------------------------------------------------
// MFMA flash attention (causal GQA), all-bf16, bf16 output. (Unchanged R7.)
// ---------------------------------------------------------------------------
__global__ __launch_bounds__(256, 2) void gqa_attn_mfma(
    const ushort* __restrict__ Qg, const ushort* __restrict__ Kgl,
    const ushort* __restrict__ Vt_g, ushort* __restrict__ O, int S) {
  __shared__ ushort Qs[64 * 128];   // chunk c of row r at c^(r&15)
  __shared__ ushort Ks[64 * 128];   // same swizzle
  __shared__ ushort Vs[128 * 64];   // V^T: chunk c of row d at c^(d&7)
  __shared__ ushort Ps[4][16][72];  // per-wave P, +8 pad

  const int tid = threadIdx.x;
  const int wave = tid >> 6;
  const int lane = tid & 63;
  const int quad = lane >> 4;
  const int lr = lane & 15;
  const int q0 = ((int)gridDim.x - 1 - (int)blockIdx.x) * 64;  // LPT
  const int hq = blockIdx.y;
  const int b = blockIdx.z;
  const int kvh = hq >> 2;
  const float scale = 0.08838834764831845f;  // 1/sqrt(128)

  const ushort* Qb = Qg + ((size_t)b * S) * (NH * HD) + (size_t)hq * HD;
  const ushort* Kb = Kgl + ((size_t)b * S) * (NKV * HD) + (size_t)kvh * HD;
  const ushort* Vb = Vt_g + ((size_t)(b * NKV + kvh) * HD) * S;

#pragma unroll
  for (int i = 0; i < 4; ++i) {
    const int id = tid + i * 256;
    const int r = id >> 4, c = id & 15;
    const int p = c ^ (r & 15);
    *reinterpret_cast<uint4*>(&Qs[r * 128 + p * 8]) =
        *reinterpret_cast<const uint4*>(
            &Qb[(size_t)(q0 + r) * (NH * HD) + c * 8]);
  }

  f32x4 oacc[8];
#pragma unroll
  for (int nb = 0; nb < 8; ++nb) oacc[nb] = (f32x4){0.f, 0.f, 0.f, 0.f};
  float m_r[4] = {-INFINITY, -INFINITY, -INFINITY, -INFINITY};
  float l_r[4] = {0.f, 0.f, 0.f, 0.f};

  const int ntiles = q0 / 64 + 1;
  for (int kt = 0; kt < ntiles; ++kt) {
    const int k0 = kt * 64;
    __syncthreads();
#pragma unroll
    for (int i = 0; i < 4; ++i) {
      const int id = tid + i * 256;
      const int r = id >> 4, c = id & 15;
      const int p = c ^ (r & 15);
      *reinterpret_cast<uint4*>(&Ks[r * 128 + p * 8]) =
          *reinterpret_cast<const uint4*>(
              &Kb[(size_t)(k0 + r) * (NKV * HD) + c * 8]);
    }
#pragma unroll
    for (int i = 0; i < 4; ++i) {
      const int id = tid + i * 256;
      const int d = id >> 3, c = id & 7;
      const int p = c ^ (d & 7);
      *reinterpret_cast<uint4*>(&Vs[d * 64 + p * 8]) =
          *reinterpret_cast<const uint4*>(&Vb[(size_t)d * S + k0 + c * 8]);
    }
    __syncthreads();

    // ---- QK^T ----
    short8v aq[4];
#pragma unroll
    for (int ks = 0; ks < 4; ++ks) {
      const int ra = wave * 16 + lr;
      aq[ks] = *reinterpret_cast<const short8v*>(
          &Qs[ra * 128 + (((ks * 4 + quad) ^ lr) & 15) * 8]);
    }
    f32x4 sacc[4];
#pragma unroll
    for (int nb = 0; nb < 4; ++nb) {
      sacc[nb] = (f32x4){0.f, 0.f, 0.f, 0.f};
      const int rb = nb * 16 + lr;
#pragma unroll
      for (int ks = 0; ks < 4; ++ks) {
        short8v bk = *reinterpret_cast<const short8v*>(
            &Ks[rb * 128 + (((ks * 4 + quad) ^ lr) & 15) * 8]);
        sacc[nb] = __builtin_amdgcn_mfma_f32_16x16x32_bf16(
            aq[ks], bk, sacc[nb], 0, 0, 0);
      }
    }

    // ---- register softmax ----
    const bool diag = (kt == ntiles - 1);
    float pmat[4][4];
    float alpha[4];
#pragma unroll
    for (int rg = 0; rg < 4; ++rg) {
      float mx = -INFINITY;
#pragma unroll
      for (int nb = 0; nb < 4; ++nb) {
        float sv = sacc[nb][rg] * scale;
        if (diag) {
          const int kj = k0 + nb * 16 + lr;
          const int qi = q0 + wave * 16 + quad * 4 + rg;
          if (kj > qi) sv = -1e30f;
        }
        pmat[nb][rg] = sv;
        mx = fmaxf(mx, sv);
      }
      mx = fmaxf(mx, __shfl_xor(mx, 1));
      mx = fmaxf(mx, __shfl_xor(mx, 2));
      mx = fmaxf(mx, __shfl_xor(mx, 4));
      mx = fmaxf(mx, __shfl_xor(mx, 8));
      const float mn = fmaxf(m_r[rg], mx);
      alpha[rg] = __expf(m_r[rg] - mn);
      m_r[rg] = mn;
      float rs = 0.f;
#pragma unroll
      for (int nb = 0; nb < 4; ++nb) {
        const float p = __expf(pmat[nb][rg] - mn);
        pmat[nb][rg] = p;
        rs += p;
      }
      rs += __shfl_xor(rs, 1);
      rs += __shfl_xor(rs, 2);
      rs += __shfl_xor(rs, 4);
      rs += __shfl_xor(rs, 8);
      l_r[rg] = l_r[rg] * alpha[rg] + rs;
    }

    // P -> LDS (D-layout write, A-layout read)
#pragma unroll
    for (int rg = 0; rg < 4; ++rg)
#pragma unroll
      for (int nb = 0; nb < 4; ++nb)
        Ps[wave][quad * 4 + rg][nb * 16 + lr] = f2bf(pmat[nb][rg]);

#pragma unroll
    for (int nb = 0; nb < 8; ++nb)
#pragma unroll
      for (int rg = 0; rg < 4; ++rg) oacc[nb][rg] *= alpha[rg];

    __syncthreads();  // fence: P ushort stores -> short8v loads (TBAA)

    // ---- PV ----
    short8v ap[2];
#pragma unroll
    for (int ks = 0; ks < 2; ++ks)
      ap[ks] = *reinterpret_cast<const short8v*>(
          &Ps[wave][lr][ks * 32 + quad * 8]);
#pragma unroll
    for (int nb = 0; nb < 8; ++nb) {
      const int rv = nb * 16 + lr;
#pragma unroll
      for (int ks = 0; ks < 2; ++ks) {
        short8v bv = *reinterpret_cast<const short8v*>(
            &Vs[rv * 64 + (((ks * 4 + quad) ^ lr) & 7) * 8]);
        oacc[nb] = __builtin_amdgcn_mfma_f32_16x16x32_bf16(
            ap[ks], bv, oacc[nb], 0, 0, 0);
      }
    }
  }

  // ---- epilogue ----
  __syncthreads();
  float inv[4];
#pragma unroll
  for (int rg = 0; rg < 4; ++rg) inv[rg] = 1.0f / l_r[rg];
  ushort* ow = &Qs[wave * 16 * 128];
#pragma unroll
  for (int nb = 0; nb < 8; ++nb)
#pragma unroll
    for (int rg = 0; rg < 4; ++rg)
      ow[(quad * 4 + rg) * 128 + nb * 16 + lr] = f2bf(oacc[nb][rg] * inv[rg]);
  __syncthreads();  // fence: ushort stores -> uint4 loads (TBAA)
  ushort* Ob = O + ((size_t)b * S) * (NH * HD) + (size_t)hq * HD;
#pragma unroll
  for (int ii = 0; ii < 4; ++ii) {
    const int id = lane + ii * 64;
    const int r16 = id >> 4, c = id & 15;
    uint4 val = *reinterpret_cast<const uint4*>(&ow[r16 * 128 + c * 8]);
    *reinterpret_cast<uint4*>(
        &Ob[(size_t)(q0 + wave * 16 + r16) * (NH * HD) + c * 8]) = val;
  }
}

// ---------------------------------------------------------------------------
extern "C" void kernel_launch(void* const* d_in, const int* in_sizes, int n_in,
                              void* d_out, int out_size, void* d_ws,
                              size_t ws_size, hipStream_t stream) {
  const float* x = (const float*)d_in[0];
  const float* wq = (const float*)d_in[1];
  const float* bq = (const float*)d_in[2];
  const float* wk = (const float*)d_in[3];
  const float* bk = (const float*)d_in[4];
  const float* wv = (const float*)d_in[5];
  const float* bv = (const float*)d_in[6];
  const float* wo = (const float*)d_in[7];
  const float* bo = (const float*)d_in[8];
  float* out = (float*)d_out;

  const int M = in_sizes[0] / HID;  // B*S = 4096
  const int S = M / BATCH;          // 2048

  // Workspace (76 MB)
  char* w = (char*)d_ws;
  ushort* xb    = (ushort*)(w + 0);            // 16 MB bf16 [M][2048]
  ushort* qb    = (ushort*)(w + (16u << 20));  // 16 MB bf16 [M][2048]
  ushort* kb    = (ushort*)(w + (32u << 20));  //  4 MB bf16 [M][512]
  ushort* vT    = (ushort*)(w + (36u << 20));  //  4 MB bf16 [B][NKV][HD][S]
  ushort* attnb = (ushort*)(w + (40u << 20));  // 16 MB bf16 [M][2048]
  ushort* wqT   = (ushort*)(w + (56u << 20));  //  8 MB bf16 [2048][2048]
  ushort* wkT   = (ushort*)(w + (64u << 20));  //  2 MB bf16 [512][2048]
  ushort* wvT   = (ushort*)(w + (66u << 20));  //  2 MB bf16 [512][2048]
  ushort* woT   = (ushort*)(w + (68u << 20));  //  8 MB bf16 [2048][2048]

  dim3 blk(256);
  // Input cast + weight transpose-casts
  castx_kernel<<<dim3((M * HID) / (8 * 256)), blk, 0, stream>>>(x, xb);
  tcast_kernel<<<dim3(HID / 32, (NH * HD) / 32), blk, 0, stream>>>(
      wq, wqT, HID, NH * HD);
  tcast_kernel<<<dim3(HID / 32, (NKV * HD) / 32), blk, 0, stream>>>(
      wk, wkT, HID, NKV * HD);
  tcast_kernel<<<dim3(HID / 32, (NKV * HD) / 32), blk, 0, stream>>>(
      wv, wvT, HID, NKV * HD);
  tcast_kernel<<<dim3(HID / 32, HID / 32), blk, 0, stream>>>(
      wo, woT, HID, HID);

  // Fused QKV projection: 24x32 = 768 blocks
  gemm_big<1><<<dim3(3072 / 128, M / 128), blk, 0, stream>>>(
      xb, wqT, wkT, wvT, bq, bk, bv, qb, kb, vT, M, HID, S);

  // MFMA flash attention
  gqa_attn_mfma<<<dim3(S / 64, NH, BATCH), blk, 0, stream>>>(
      qb, kb, vT, attnb, S);

  // Output projection (fp32 out)
  gemm_big<0><<<dim3(HID / 128, M / 128), blk, 0, stream>>>(
      attnb, woT, nullptr, nullptr, bo, nullptr, nullptr,
      out, nullptr, nullptr, M, HID, S);
}